// Round 2
// baseline (237.518 us; speedup 1.0000x reference)
//
#include <hip/hip_runtime.h>
#include <math.h>

#define N_NODES 20000
#define K_NB 8
#define IN_F 128
#define H_F 128
#define RPB 16   // rows per block in GEMM kernel

// ---------------------------------------------------------------------------
// Kernel 1: fused self_h/Wh1/Wh2 GEMMs + bias.
//   thread t: w = t>>7 selects W0/W1/W2, col = t&127 the output column.
//   Writes: out[:,0:128] = relu(self_h); ws Wh1, Wh2 (raw); ws eh = self_h.a_h
// ---------------------------------------------------------------------------
__global__ __launch_bounds__(384) void k_gemm(
    const float* __restrict__ feat,
    const float* __restrict__ W0, const float* __restrict__ b0,
    const float* __restrict__ W1, const float* __restrict__ b1,
    const float* __restrict__ W2, const float* __restrict__ b2,
    const float* __restrict__ attn_w,
    float* __restrict__ out,
    float* __restrict__ Wh1, float* __restrict__ Wh2,
    float* __restrict__ ehw)
{
    __shared__ float ldsFeat[RPB * IN_F];
    __shared__ float ehp[2][RPB];

    const int t = threadIdx.x;
    const int row0 = blockIdx.x * RPB;

    for (int idx = t; idx < RPB * IN_F; idx += 384)
        ldsFeat[idx] = feat[(size_t)row0 * IN_F + idx];
    __syncthreads();

    const int w   = t >> 7;     // 0,1,2
    const int col = t & 127;
    const float* W = (w == 0) ? W0 : (w == 1) ? W1 : W2;

    float acc[RPB];
    #pragma unroll
    for (int r = 0; r < RPB; ++r) acc[r] = 0.f;

    // K=128 in 4 chunks of 32; W column chunk in registers, feat broadcast from LDS
    for (int c = 0; c < 4; ++c) {
        float wreg[32];
        #pragma unroll
        for (int i = 0; i < 32; ++i)
            wreg[i] = W[(size_t)(c * 32 + i) * H_F + col];
        #pragma unroll
        for (int r = 0; r < RPB; ++r) {
            const float4* f4 = reinterpret_cast<const float4*>(&ldsFeat[r * IN_F + c * 32]);
            #pragma unroll
            for (int i4 = 0; i4 < 8; ++i4) {
                float4 f = f4[i4];
                acc[r] = fmaf(f.x, wreg[i4 * 4 + 0], acc[r]);
                acc[r] = fmaf(f.y, wreg[i4 * 4 + 1], acc[r]);
                acc[r] = fmaf(f.z, wreg[i4 * 4 + 2], acc[r]);
                acc[r] = fmaf(f.w, wreg[i4 * 4 + 3], acc[r]);
            }
        }
    }

    if (w == 0) {
        const float bias = b0[col];
        const float ah   = attn_w[H_F + col];   // a_h = attn_w[128:256]
        float p[RPB];
        #pragma unroll
        for (int r = 0; r < RPB; ++r) {
            float v = acc[r] + bias;                       // self_h (pre-relu)
            out[(size_t)(row0 + r) * 256 + col] = fmaxf(v, 0.f);
            p[r] = v * ah;                                 // eh uses PRE-relu self_h
        }
        // reduce p over the 128 w==0 threads (waves 0 and 1)
        #pragma unroll
        for (int off = 32; off >= 1; off >>= 1) {
            #pragma unroll
            for (int r = 0; r < RPB; ++r)
                p[r] += __shfl_down(p[r], off, 64);
        }
        if ((t & 63) == 0) {
            const int wv = t >> 6;   // 0 or 1
            #pragma unroll
            for (int r = 0; r < RPB; ++r) ehp[wv][r] = p[r];
        }
    } else if (w == 1) {
        const float bias = b1[col];
        #pragma unroll
        for (int r = 0; r < RPB; ++r)
            Wh1[(size_t)(row0 + r) * H_F + col] = acc[r] + bias;
    } else {
        const float bias = b2[col];
        #pragma unroll
        for (int r = 0; r < RPB; ++r)
            Wh2[(size_t)(row0 + r) * H_F + col] = acc[r] + bias;
    }
    __syncthreads();
    if (t < RPB)
        ehw[row0 + t] = ehp[0][t] + ehp[1][t];
}

// ---------------------------------------------------------------------------
// Kernel 2: per-node gather + distance-softmax aggregation. 1 block / node.
//   LDS rows 0..15  = Z  (z1 = Wh1[src1], z2 = Wh2[src2])
//   LDS rows 16..31 = M  (m1 = Wh1[src2], m2 = Wh2[src1])
// ---------------------------------------------------------------------------
#define LDM 132   // padded row stride (floats): 132*4B=528B, 528%16==0, ≤2-way banks

__global__ __launch_bounds__(256) void k_agg(
    const float* __restrict__ Wh1, const float* __restrict__ Wh2,
    const float* __restrict__ ehw, const float* __restrict__ attn_w,
    const int* __restrict__ src1, const int* __restrict__ src2,
    float* __restrict__ out)
{
    __shared__ float ZM[32][LDM];
    __shared__ float sq[32];      // |row|^2
    __shared__ float za[16];      // z_d . a_z
    __shared__ float msum[16];    // sum of m row (mask source)
    __shared__ float ev[16];      // e_d = leaky_relu(za+eh)
    __shared__ float bwv[32];
    __shared__ float fbw[16];

    const int n = blockIdx.x;
    const int t = threadIdx.x;

    // ---- gather 32 rows of 128 floats (float4, 8 rows per pass) ----
    {
        const int lane = t & 31;
        #pragma unroll
        for (int p = 0; p < 4; ++p) {
            const int r = p * 8 + (t >> 5);
            int idx; const float* srcp;
            if (r < 8)       { idx = src1[n * K_NB + r];      srcp = Wh1; }
            else if (r < 16) { idx = src2[n * K_NB + r - 8];  srcp = Wh2; }
            else if (r < 24) { idx = src2[n * K_NB + r - 16]; srcp = Wh1; }
            else             { idx = src1[n * K_NB + r - 24]; srcp = Wh2; }
            float4 v = reinterpret_cast<const float4*>(srcp + (size_t)idx * H_F)[lane];
            *reinterpret_cast<float4*>(&ZM[r][lane * 4]) = v;
        }
    }
    __syncthreads();

    // ---- per-row stats: |.|^2, z.a_z (rows<16), sum (rows>=16) ----
    {
        const int r = t >> 3, j = t & 7;
        const float* az = attn_w;          // a_z = attn_w[0:128]
        float s_sq = 0.f, s_za = 0.f, s_sum = 0.f;
        #pragma unroll
        for (int q = 0; q < 4; ++q) {
            const int k = j * 16 + q * 4;
            float4 v = *reinterpret_cast<const float4*>(&ZM[r][k]);
            s_sq += v.x * v.x + v.y * v.y + v.z * v.z + v.w * v.w;
            if (r < 16)
                s_za += v.x * az[k] + v.y * az[k + 1] + v.z * az[k + 2] + v.w * az[k + 3];
            else
                s_sum += v.x + v.y + v.z + v.w;
        }
        #pragma unroll
        for (int off = 1; off < 8; off <<= 1) {
            s_sq  += __shfl_xor(s_sq,  off, 64);
            s_za  += __shfl_xor(s_za,  off, 64);
            s_sum += __shfl_xor(s_sum, off, 64);
        }
        if (j == 0) {
            sq[r] = s_sq;
            if (r < 16) za[r] = s_za; else msum[r - 16] = s_sum;
        }
    }
    __syncthreads();

    const float ehn = ehw[n];
    if (t < 16) {
        float x = za[t] + ehn;
        ev[t] = (x > 0.f) ? x : 0.01f * x;   // leaky_relu(...,0.01)
    }
    __syncthreads();

    // ---- 16x16 dots, aw, bw rows ----
    {
        const int d = t >> 4, e = t & 15;
        const float4* zr = reinterpret_cast<const float4*>(&ZM[d][0]);
        const float4* mr = reinterpret_cast<const float4*>(&ZM[16 + e][0]);
        float dot = 0.f;
        #pragma unroll
        for (int k4 = 0; k4 < 32; ++k4) {
            float4 a = zr[k4]; float4 b = mr[k4];
            dot += a.x * b.x + a.y * b.y + a.z * b.z + a.w * b.w;
        }
        float d2  = sq[d] + sq[16 + e] - 2.f * dot;
        float awq = expf(-sqrtf(fmaxf(d2, 1e-12f)));
        float bwp = (msum[e] != 0.f) ? awq : 0.f;
        #pragma unroll
        for (int off = 1; off < 16; off <<= 1)
            bwp += __shfl_xor(bwp, off, 64);
        if (e == 0) bwv[d] = bwp;
    }
    // degenerate d>=16 rows of bw: only nonzero when that m-row sums to 0
    if (t < 16) {
        float v = 0.f;
        if (msum[t] == 0.f) {
            for (int e = 0; e < 16; ++e)
                if (msum[e] != 0.f)
                    v += expf(-sqrtf(fmaxf(sq[16 + e], 1e-12f)));
        }
        bwv[16 + t] = v;
    }
    __syncthreads();

    // ---- normalize exactly as reference: /S1, *softmax(emb), /S2 ----
    if (t < 32) {
        float bwt = bwv[t];
        float S1 = bwt;
        #pragma unroll
        for (int off = 1; off < 32; off <<= 1) S1 += __shfl_xor(S1, off, 64);
        bwt /= S1;

        float embt = (t < 16) ? ev[t] : 0.f;
        float mx = embt;
        #pragma unroll
        for (int off = 1; off < 32; off <<= 1) mx = fmaxf(mx, __shfl_xor(mx, off, 64));
        float ex = expf(embt - mx);
        float A = ex;
        #pragma unroll
        for (int off = 1; off < 32; off <<= 1) A += __shfl_xor(A, off, 64);
        float alpha = ex / A;

        float bw2 = bwt * alpha;
        float S2 = bw2;
        #pragma unroll
        for (int off = 1; off < 32; off <<= 1) S2 += __shfl_xor(S2, off, 64);
        float f = bw2 / S2;
        if (t < 16) fbw[t] = f;
    }
    __syncthreads();

    // ---- agg[h] = sum_d fbw[d] * Z[d][h]; out second half = relu(agg) ----
    if (t < 128) {
        float a = 0.f;
        #pragma unroll
        for (int d = 0; d < 16; ++d)
            a = fmaf(fbw[d], ZM[d][t], a);
        out[(size_t)n * 256 + 128 + t] = fmaxf(a, 0.f);
    }
}

// ---------------------------------------------------------------------------
extern "C" void kernel_launch(void* const* d_in, const int* in_sizes, int n_in,
                              void* d_out, int out_size, void* d_ws, size_t ws_size,
                              hipStream_t stream) {
    const float* feat   = (const float*)d_in[0];
    const float* W0     = (const float*)d_in[1];
    const float* b0     = (const float*)d_in[2];
    const float* W1     = (const float*)d_in[3];
    const float* b1     = (const float*)d_in[4];
    const float* W2     = (const float*)d_in[5];
    const float* b2     = (const float*)d_in[6];
    const float* attn_w = (const float*)d_in[7];
    const int*   src1   = (const int*)d_in[8];
    const int*   src2   = (const int*)d_in[9];
    float* out = (float*)d_out;

    float* Wh1 = (float*)d_ws;
    float* Wh2 = Wh1 + (size_t)N_NODES * H_F;
    float* ehw = Wh2 + (size_t)N_NODES * H_F;

    k_gemm<<<N_NODES / RPB, 384, 0, stream>>>(feat, W0, b0, W1, b1, W2, b2,
                                              attn_w, out, Wh1, Wh2, ehw);
    k_agg<<<N_NODES, 256, 0, stream>>>(Wh1, Wh2, ehw, attn_w, src1, src2, out);
}

// Round 3
// 189.125 us; speedup vs baseline: 1.2559x; 1.2559x over previous
//
#include <hip/hip_runtime.h>
#include <math.h>

#define N_NODES 20000
#define K_NB 8
#define IN_F 128
#define H_F 128

typedef __attribute__((ext_vector_type(8))) short bf16x8;
typedef __attribute__((ext_vector_type(4))) float f32x4;

// split fp32 -> bf16 hi + bf16 lo (truncation; v = hi + lo + O(2^-16 v))
__device__ __forceinline__ void split8(const float* v, bf16x8& h, bf16x8& l) {
#pragma unroll
    for (int j = 0; j < 8; ++j) {
        unsigned u = __float_as_uint(v[j]);
        h[j] = (short)(u >> 16);
        float rr = v[j] - __uint_as_float(u & 0xFFFF0000u);
        l[j] = (short)(__float_as_uint(rr) >> 16);
    }
}

__device__ __forceinline__ float bf2f(short s) {
    return __uint_as_float(((unsigned)(unsigned short)s) << 16);
}

// ---------------------------------------------------------------------------
// Prep: Wt_hi/Wt_lo[col=0..383][k=0..127] = bf16-split of W{0,1,2}^T
// ---------------------------------------------------------------------------
__global__ __launch_bounds__(256) void k_prep(
    const float* __restrict__ W0, const float* __restrict__ W1,
    const float* __restrict__ W2,
    unsigned short* __restrict__ Wt_hi, unsigned short* __restrict__ Wt_lo)
{
    int id = blockIdx.x * 256 + threadIdx.x;      // 49152 = 128*384
    int k = id / 384;
    int col = id - k * 384;
    const float* W = (col < 128) ? W0 : (col < 256) ? W1 : W2;
    float v = W[k * IN_F + (col & 127)];
    unsigned u = __float_as_uint(v);
    Wt_hi[col * 128 + k] = (unsigned short)(u >> 16);
    float r = v - __uint_as_float(u & 0xFFFF0000u);
    Wt_lo[col * 128 + k] = (unsigned short)(__float_as_uint(r) >> 16);
}

// ---------------------------------------------------------------------------
// Kernel 1: MFMA bf16x3 GEMM. 1 block = 16 rows; 4 waves x 6 col-tiles = 384 cols.
//   tiles 0-7 -> self_h (relu to out, + eh dot), 8-15 -> Wh1, 16-23 -> Wh2
// ---------------------------------------------------------------------------
__global__ __launch_bounds__(256) void k_gemm(
    const float* __restrict__ feat,
    const unsigned short* __restrict__ Wt_hi, const unsigned short* __restrict__ Wt_lo,
    const float* __restrict__ b0, const float* __restrict__ b1,
    const float* __restrict__ b2, const float* __restrict__ attn_w,
    float* __restrict__ out, float* __restrict__ Wh1, float* __restrict__ Wh2,
    float* __restrict__ ehw)
{
    __shared__ float ehp[4][16];
    const int t = threadIdx.x;
    const int wv = t >> 6, l = t & 63;
    const int r = l & 15, g = l >> 4;       // A row in tile, k-chunk
    const int row0 = blockIdx.x * 16;

    // A fragments (feat rows, f32 -> bf16 hi/lo)
    bf16x8 fh[4], fl[4];
    {
        const float* fp = feat + (size_t)(row0 + r) * IN_F + g * 8;
#pragma unroll
        for (int kk = 0; kk < 4; ++kk) {
            float av[8];
            *(float4*)(av)     = *(const float4*)(fp + kk * 32);
            *(float4*)(av + 4) = *(const float4*)(fp + kk * 32 + 4);
            split8(av, fh[kk], fl[kk]);
        }
    }

    float ehacc[4] = {0.f, 0.f, 0.f, 0.f};

    for (int c = wv * 6; c < wv * 6 + 6; ++c) {
        const int gc = c * 16 + r;          // global output column (B row of Wt)
        const bf16x8* bh = (const bf16x8*)(Wt_hi + (size_t)gc * 128 + g * 8);
        const bf16x8* bl = (const bf16x8*)(Wt_lo + (size_t)gc * 128 + g * 8);
        f32x4 acc = {0.f, 0.f, 0.f, 0.f};
#pragma unroll
        for (int kk = 0; kk < 4; ++kk) {
            bf16x8 wh = bh[kk * 4];         // +kk*32 elements
            bf16x8 wl = bl[kk * 4];
            acc = __builtin_amdgcn_mfma_f32_16x16x32_bf16(fh[kk], wh, acc, 0, 0, 0);
            acc = __builtin_amdgcn_mfma_f32_16x16x32_bf16(fh[kk], wl, acc, 0, 0, 0);
            acc = __builtin_amdgcn_mfma_f32_16x16x32_bf16(fl[kk], wh, acc, 0, 0, 0);
        }
        const int widx = c >> 3;
        const int lc = gc & 127;
        if (widx == 0) {
            const float bias = b0[lc];
            const float ah = attn_w[H_F + lc];
#pragma unroll
            for (int rr = 0; rr < 4; ++rr) {
                float v = acc[rr] + bias;   // self_h pre-relu
                out[(size_t)(row0 + g * 4 + rr) * 256 + lc] = fmaxf(v, 0.f);
                ehacc[rr] += v * ah;        // eh uses PRE-relu self_h
            }
        } else {
            float* Wh = (widx == 1) ? Wh1 : Wh2;
            const float bias = (widx == 1) ? b1[lc] : b2[lc];
#pragma unroll
            for (int rr = 0; rr < 4; ++rr)
                Wh[(size_t)(row0 + g * 4 + rr) * H_F + lc] = acc[rr] + bias;
        }
    }

    // eh: reduce over the 16 cols held by this 16-lane group, then across waves
#pragma unroll
    for (int off = 1; off <= 8; off <<= 1)
#pragma unroll
        for (int rr = 0; rr < 4; ++rr)
            ehacc[rr] += __shfl_xor(ehacc[rr], off, 64);
    if (r == 0) {
#pragma unroll
        for (int rr = 0; rr < 4; ++rr) ehp[wv][g * 4 + rr] = ehacc[rr];
    }
    __syncthreads();
    if (t < 16)
        ehw[row0 + t] = ehp[0][t] + ehp[1][t] + ehp[2][t] + ehp[3][t];
}

// ---------------------------------------------------------------------------
// Kernel 2: one WAVE per node, zero LDS. Gather loads land directly in MFMA
// fragment layout (lane l: row l&15, k-chunk (l>>4)*8). Dot tile via bf16x3
// MFMA; all reductions via shfl trees.
//   Z rows 0-7 = Wh1[src1], 8-15 = Wh2[src2]
//   M rows 0-7 = Wh1[src2], 8-15 = Wh2[src1]
// ---------------------------------------------------------------------------
__global__ __launch_bounds__(256) void k_agg(
    const float* __restrict__ Wh1, const float* __restrict__ Wh2,
    const float* __restrict__ ehw, const float* __restrict__ attn_w,
    const int* __restrict__ src1, const int* __restrict__ src2,
    float* __restrict__ out)
{
    const int t = threadIdx.x;
    const int wv = t >> 6, l = t & 63;
    const int n = blockIdx.x * 4 + wv;
    const int r = l & 15, g = l >> 4;

    const int j8 = r & 7;
    const int s1 = src1[n * K_NB + j8];
    const int s2 = src2[n * K_NB + j8];
    const int zidx = (r < 8) ? s1 : s2;
    const int midx = (r < 8) ? s2 : s1;
    const float* zp = ((r < 8) ? Wh1 : Wh2) + (size_t)zidx * H_F + g * 8;
    const float* mp = ((r < 8) ? Wh1 : Wh2) + (size_t)midx * H_F + g * 8;
    const float* ap = attn_w + g * 8;

    bf16x8 zh[4], zl[4], mh[4], ml[4];
    float sqz = 0.f, sqm = 0.f, za = 0.f, msum = 0.f;
#pragma unroll
    for (int kk = 0; kk < 4; ++kk) {
        float zv[8], mv[8], av[8];
        *(float4*)zv       = *(const float4*)(zp + kk * 32);
        *(float4*)(zv + 4) = *(const float4*)(zp + kk * 32 + 4);
        *(float4*)mv       = *(const float4*)(mp + kk * 32);
        *(float4*)(mv + 4) = *(const float4*)(mp + kk * 32 + 4);
        *(float4*)av       = *(const float4*)(ap + kk * 32);
        *(float4*)(av + 4) = *(const float4*)(ap + kk * 32 + 4);
#pragma unroll
        for (int j = 0; j < 8; ++j) {
            sqz = fmaf(zv[j], zv[j], sqz);
            za  = fmaf(zv[j], av[j], za);
            sqm = fmaf(mv[j], mv[j], sqm);
            msum += mv[j];
        }
        split8(zv, zh[kk], zl[kk]);
        split8(mv, mh[kk], ml[kk]);
    }
    // reduce partial sums across the 4 lanes holding the same row (xor 16,32)
    sqz  += __shfl_xor(sqz, 16, 64);  sqz  += __shfl_xor(sqz, 32, 64);
    za   += __shfl_xor(za,  16, 64);  za   += __shfl_xor(za,  32, 64);
    sqm  += __shfl_xor(sqm, 16, 64);  sqm  += __shfl_xor(sqm, 32, 64);
    msum += __shfl_xor(msum,16, 64);  msum += __shfl_xor(msum,32, 64);

    const float eh = ehw[n];
    float ev = za + eh;
    ev = (ev > 0.f) ? ev : 0.01f * ev;          // leaky_relu

    // D[i][j] = Z_i . M_j  (i=(l>>4)*4+reg, j=l&15)
    f32x4 acc = {0.f, 0.f, 0.f, 0.f};
#pragma unroll
    for (int kk = 0; kk < 4; ++kk) {
        acc = __builtin_amdgcn_mfma_f32_16x16x32_bf16(zh[kk], mh[kk], acc, 0, 0, 0);
        acc = __builtin_amdgcn_mfma_f32_16x16x32_bf16(zh[kk], ml[kk], acc, 0, 0, 0);
        acc = __builtin_amdgcn_mfma_f32_16x16x32_bf16(zl[kk], mh[kk], acc, 0, 0, 0);
    }

    // bw rows 0..15 (z-part): sum over m-cols j of masked exp(-sqrt(d2))
    float bwz[4];
#pragma unroll
    for (int rr = 0; rr < 4; ++rr) {
        const int i = g * 4 + rr;
        float sqzi = __shfl(sqz, i, 64);
        float d2 = sqzi + sqm - 2.f * acc[rr];
        float aw = __expf(-sqrtf(fmaxf(d2, 1e-12f)));
        float cv = (msum != 0.f) ? aw : 0.f;
#pragma unroll
        for (int off = 1; off <= 8; off <<= 1) cv += __shfl_xor(cv, off, 64);
        bwz[rr] = cv;                            // uniform within 16-lane group
    }
    // degenerate rows 16..31: zmb row is zero -> d2 = |m_e|^2
    float td = (msum != 0.f) ? __expf(-sqrtf(fmaxf(sqm, 1e-12f))) : 0.f;
#pragma unroll
    for (int off = 1; off <= 8; off <<= 1) td += __shfl_xor(td, off, 64);
    float bwdeg = (msum == 0.f) ? td : 0.f;      // row 16+r

    // S1 = sum of all 32 bw entries
    float s1p = bwz[0] + bwz[1] + bwz[2] + bwz[3];
    s1p += __shfl_xor(s1p, 16, 64); s1p += __shfl_xor(s1p, 32, 64);
    float s1d = bwdeg;
#pragma unroll
    for (int off = 1; off <= 8; off <<= 1) s1d += __shfl_xor(s1d, off, 64);
    const float S1 = s1p + s1d;

    // softmax over emb = [ev_0..ev_15, 0 x16]
    float mx = ev;
#pragma unroll
    for (int off = 1; off <= 8; off <<= 1) mx = fmaxf(mx, __shfl_xor(mx, off, 64));
    mx = fmaxf(mx, 0.f);
    float exm = __expf(ev - mx);
    float A = exm;
#pragma unroll
    for (int off = 1; off <= 8; off <<= 1) A += __shfl_xor(A, off, 64);
    const float e0 = __expf(-mx);
    A += 16.f * e0;

    // bw2 = (bw/S1)*alpha ; S2 = sum
    float bw2[4];
    float s2p = 0.f;
#pragma unroll
    for (int rr = 0; rr < 4; ++rr) {
        const int i = g * 4 + rr;
        float evi = __shfl(ev, i, 64);
        float al = __expf(evi - mx) / A;
        bw2[rr] = (bwz[rr] / S1) * al;
        s2p += bw2[rr];
    }
    s2p += __shfl_xor(s2p, 16, 64); s2p += __shfl_xor(s2p, 32, 64);
    float s2d = (bwdeg / S1) * (e0 / A);
#pragma unroll
    for (int off = 1; off <= 8; off <<= 1) s2d += __shfl_xor(s2d, off, 64);
    const float S2 = s2p + s2d;

    // fbw for my row r: bw2[r&3] lives (group-uniform) in group r>>2
    const int rsel = r & 3;
    float myb = (rsel == 0) ? bw2[0] : (rsel == 1) ? bw2[1]
              : (rsel == 2) ? bw2[2] : bw2[3];
    const float fbw = __shfl(myb, ((r >> 2) << 4) | rsel, 64) / S2;

    // agg[k] = sum_r fbw[r] * Z[r][k]; relu; store
    float* op = out + (size_t)n * 256 + 128;
#pragma unroll
    for (int kk = 0; kk < 4; ++kk) {
        float vj[8];
#pragma unroll
        for (int j = 0; j < 8; ++j) {
            float zval = bf2f(zh[kk][j]) + bf2f(zl[kk][j]);
            vj[j] = fbw * zval;
        }
#pragma unroll
        for (int off = 1; off <= 8; off <<= 1)
#pragma unroll
            for (int j = 0; j < 8; ++j)
                vj[j] += __shfl_xor(vj[j], off, 64);
        if (r == 0) {
            float4 o0 = {fmaxf(vj[0], 0.f), fmaxf(vj[1], 0.f),
                         fmaxf(vj[2], 0.f), fmaxf(vj[3], 0.f)};
            float4 o1 = {fmaxf(vj[4], 0.f), fmaxf(vj[5], 0.f),
                         fmaxf(vj[6], 0.f), fmaxf(vj[7], 0.f)};
            *(float4*)(op + kk * 32 + g * 8)     = o0;
            *(float4*)(op + kk * 32 + g * 8 + 4) = o1;
        }
    }
}

// ---------------------------------------------------------------------------
extern "C" void kernel_launch(void* const* d_in, const int* in_sizes, int n_in,
                              void* d_out, int out_size, void* d_ws, size_t ws_size,
                              hipStream_t stream) {
    const float* feat   = (const float*)d_in[0];
    const float* W0     = (const float*)d_in[1];
    const float* b0     = (const float*)d_in[2];
    const float* W1     = (const float*)d_in[3];
    const float* b1     = (const float*)d_in[4];
    const float* W2     = (const float*)d_in[5];
    const float* b2     = (const float*)d_in[6];
    const float* attn_w = (const float*)d_in[7];
    const int*   src1   = (const int*)d_in[8];
    const int*   src2   = (const int*)d_in[9];
    float* out = (float*)d_out;

    float* Wh1 = (float*)d_ws;                                   // 20000x128 f32
    float* Wh2 = Wh1 + (size_t)N_NODES * H_F;                    // 20000x128 f32
    float* ehw = Wh2 + (size_t)N_NODES * H_F;                    // 20000 f32
    unsigned short* Wt_hi = (unsigned short*)(ehw + N_NODES);    // 384x128 bf16
    unsigned short* Wt_lo = Wt_hi + 384 * 128;                   // 384x128 bf16

    k_prep<<<192, 256, 0, stream>>>(W0, W1, W2, Wt_hi, Wt_lo);
    k_gemm<<<N_NODES / 16, 256, 0, stream>>>(feat, Wt_hi, Wt_lo, b0, b1, b2,
                                             attn_w, out, Wh1, Wh2, ehw);
    k_agg<<<N_NODES / 4, 256, 0, stream>>>(Wh1, Wh2, ehw, attn_w, src1, src2, out);
}